// Round 5
// baseline (615.280 us; speedup 1.0000x reference)
//
#include <hip/hip_runtime.h>

// LSTM, B=4096, T=2048, IN=3, H=4. R2 datapath (best so far: 205us at
// 1 wave/SIMD), relaunched for wave-level latency hiding: 64 blocks x 1024
// threads = 16 waves/CU = 4 waves/SIMD on 64 CUs. Each 16-lane group owns one
// batch element; lane l=4q+j computes the full unit-j recurrence via DPP
// (quad_perm h-broadcasts, row_ror gate gathers). With W=4 waves/SIMD the
// hardware fills each chain's trans-latency stalls with other waves' issue:
// per-step wall = max(L/4, I) ~= 65-75cy vs R2's 240cy.
// R3/R4 lesson: static dual-chain ILP gets re-serialized; TLP doesn't.

static constexpr int T_STEPS = 2048;
static constexpr int CHUNK   = 16;              // timesteps per x-staging chunk
static constexpr int NCHUNK  = T_STEPS / CHUNK; // 128

template<int CTRL>
__device__ __forceinline__ float dpp_f(float v) {
    return __int_as_float(__builtin_amdgcn_update_dpp(
        0, __float_as_int(v), CTRL, 0xF, 0xF, false));
}

struct Ctx {
    float wih0, wih1, wih2;        // pre-scaled by per-lane activation slope m
    float whh0, whh1, whh2, whh3;  // pre-scaled by m
    float Aa, Bb;                  // act = Aa * rcp(1+exp2(gp)) + Bb
    bool  b0, b1fo;                // gate-quadrant mux bits (b1fo absorbs DPP dir)
};

template<int J>
__device__ __forceinline__ float comp(const float4& v) {
    if constexpr (J == 0) return v.x;
    else if constexpr (J == 1) return v.y;
    else if constexpr (J == 2) return v.z;
    else return v.w;
}

// xp[TT] = m * (w_ih . x_t) for the 16 steps of a staged chunk (off-chain)
template<int TT>
__device__ __forceinline__ void projx16(float (&xp)[CHUNK], const float4 (&bf)[12],
                                        const Ctx& k) {
    constexpr int j0 = 3 * TT, j1 = j0 + 1, j2 = j0 + 2;
    float x0 = comp<(j0 & 3)>(bf[j0 >> 2]);
    float x1 = comp<(j1 & 3)>(bf[j1 >> 2]);
    float x2 = comp<(j2 & 3)>(bf[j2 >> 2]);
    xp[TT] = fmaf(x0, k.wih0, fmaf(x1, k.wih1, x2 * k.wih2));
    if constexpr (TT + 1 < CHUNK) projx16<TT + 1>(xp, bf, k);
}

__device__ __forceinline__ void lstm_step(float xp, float& h, float& c, const Ctx& k) {
    float hb0 = dpp_f<0x00>(h);   // quad_perm broadcasts of h0..h3
    float hb1 = dpp_f<0x55>(h);
    float hb2 = dpp_f<0xAA>(h);
    float hb3 = dpp_f<0xFF>(h);

    // own-gate preactivation (pre-scaled by m)
    float p0 = fmaf(hb1, k.whh1, fmaf(hb0, k.whh0, xp));
    float p1 = fmaf(hb2, k.whh2, hb3 * k.whh3);
    float gp = p0 + p1;

    // unified activation: sigmoid (i,f,o lanes) / tanh (g lanes)
    float e   = __builtin_amdgcn_exp2f(gp);
    float act = fmaf(k.Aa, __builtin_amdgcn_rcpf(1.0f + e), k.Bb);

    // same-unit other-gate gather via row rotations (VALU-pipe DPP)
    float t1 = dpp_f<0x124>(act);   // row_ror:4
    float t2 = dpp_f<0x128>(act);   // row_ror:8
    float t3 = dpp_f<0x12C>(act);   // row_ror:12
    float prod = k.b0 ? t1 * t3 : act * t2;   // i*g (direction-invariant)
    float A  = k.b0 ? t2  : t1;
    float Bv = k.b0 ? act : t3;
    float f  = k.b1fo ? A : Bv;
    float o  = k.b1fo ? Bv : A;

    float cn = fmaf(f, c, prod);
    c = cn;
    float e2 = __builtin_amdgcn_exp2f(-2.885390081777927f * cn);
    float th = fmaf(2.0f, __builtin_amdgcn_rcpf(1.0f + e2), -1.0f);
    h = o * th;
}

template<int TT>
__device__ __forceinline__ void steps16(const float (&xp)[CHUNK], float& h, float& c,
                                        const Ctx& k) {
    lstm_step(xp[TT], h, c, k);
    if constexpr (TT + 1 < CHUNK) steps16<TT + 1>(xp, h, c, k);
}

__device__ __forceinline__ void loadbf(float4 (&bf)[12], const float4* p) {
    #pragma unroll
    for (int i = 0; i < 12; ++i) bf[i] = p[i];
}

__global__ __launch_bounds__(1024, 4) void lstm_kernel(
    const float* __restrict__ x,
    const float* __restrict__ w_ih,
    const float* __restrict__ w_hh,
    const float* __restrict__ fc_w,
    const float* __restrict__ fc_b,
    float* __restrict__ out)
{
    const int tid = threadIdx.x;
    const int l16 = tid & 15;
    const int b   = blockIdx.x * 64 + (tid >> 4);  // 64 elements per block
    const int gt  = l16 >> 2;     // gate quadrant: 0=i 1=f 2=g 3=o

    const bool is_g = (gt == 2);
    const float mm  = is_g ? -2.885390081777927f : -1.4426950408889634f;

    Ctx k;
    k.wih0 = mm * w_ih[l16 * 3 + 0];
    k.wih1 = mm * w_ih[l16 * 3 + 1];
    k.wih2 = mm * w_ih[l16 * 3 + 2];
    k.whh0 = mm * w_hh[l16 * 4 + 0];
    k.whh1 = mm * w_hh[l16 * 4 + 1];
    k.whh2 = mm * w_hh[l16 * 4 + 2];
    k.whh3 = mm * w_hh[l16 * 4 + 3];
    k.Aa = is_g ? 2.0f : 1.0f;
    k.Bb = is_g ? -1.0f : 0.0f;
    k.b0 = (gt & 1) != 0;
    {   // runtime probe for row_ror direction; folds into the f/o mux bit
        float probe = (float)l16;
        float t1p = dpp_f<0x124>(probe);
        bool dirB = (t1p == (float)((l16 + 4) & 15));
        k.b1fo = (((gt & 2) != 0) != dirB);
    }

    const float4* xb4 = reinterpret_cast<const float4*>(x + (size_t)b * (T_STEPS * 3));

    float4 bfA[12], bfB[12];        // double-buffered raw x (48 floats = 16 steps)
    float  xpA[CHUNK], xpB[CHUNK];  // double-buffered projections
    loadbf(bfA, xb4);
    loadbf(bfB, xb4 + 12);
    projx16<0>(xpA, bfA, k);

    float h = 0.f, c = 0.f;

    for (int it = 0; it < NCHUNK / 2; ++it) {
        const int ca = (2 * it + 2 < NCHUNK) ? 2 * it + 2 : NCHUNK - 1;
        loadbf(bfA, xb4 + ca * 12);
        projx16<0>(xpB, bfB, k);
        steps16<0>(xpA, h, c, k);

        const int cb = (2 * it + 3 < NCHUNK) ? 2 * it + 3 : NCHUNK - 1;
        loadbf(bfB, xb4 + cb * 12);
        projx16<0>(xpA, bfA, k);
        steps16<0>(xpB, h, c, k);
    }

    // out[b] = fc_w . h + fc_b ; lane 4m+j holds h_j -> quad reduce
    float r = h * fc_w[l16 & 3];
    r += dpp_f<0xB1>(r);   // quad_perm [1,0,3,2]
    r += dpp_f<0x4E>(r);   // quad_perm [2,3,0,1]
    if (l16 == 0) out[b] = r + fc_b[0];
}

extern "C" void kernel_launch(void* const* d_in, const int* in_sizes, int n_in,
                              void* d_out, int out_size, void* d_ws, size_t ws_size,
                              hipStream_t stream) {
    const float* x    = (const float*)d_in[0];
    const float* w_ih = (const float*)d_in[1];
    const float* w_hh = (const float*)d_in[2];
    const float* fc_w = (const float*)d_in[3];
    const float* fc_b = (const float*)d_in[4];
    float* out = (float*)d_out;

    dim3 grid(4096 / 64);   // 64 blocks, one per CU
    dim3 block(1024);       // 16 waves/CU = 4 waves/SIMD -> TLP latency hiding
    hipLaunchKernelGGL(lstm_kernel, grid, block, 0, stream,
                       x, w_ih, w_hh, fc_w, fc_b, out);
}